// Round 7
// baseline (83.385 us; speedup 1.0000x reference)
//
#include <hip/hip_runtime.h>
#include <hip/hip_bf16.h>
#include <math.h>

// Problem constants (match reference)
#define NB 8
#define NP 512
#define NL 64
#define NH 128
#define NRB 32
#define NPT 20
#define NLT 16
#define PAIRS_CAP (NP * NL)      // 32768 pairs per complex max
#define CHUNKS 512               // PAIRS_CAP / 64
#define K1 96                    // extended layer-1 K: 32 rb + 20 pt + 16 lt + pad

typedef __attribute__((ext_vector_type(8))) _Float16 h8;
typedef __attribute__((ext_vector_type(4))) float f4;

// ---------------------------------------------------------------------------
// Kernel A: fused prep. Heterogeneous 233-block kernel, 256 threads each.
//  blk 0..7    : compaction -> packed pair records {dist, (pt<<16)|lt} (8B)
//  blk 8       : zero accumulators
//  blk 9..104  : pack wt1e column k (k<32: W1c^T copy; 32..51: TP row dot;
//                52..67: TL row dot; 68..95: zero)
//  blk 105..232: pack wt2t/wt3t row k (transpose of W2/W3)
// Pair records remove ALL scattered gathers from the hot MLP kernel: its
// prologue becomes one coalesced 8B load per lane.
// ---------------------------------------------------------------------------
__global__ __launch_bounds__(256) void prep(
    const float* __restrict__ ppos, const float* __restrict__ lpos,
    const int* __restrict__ ptype_g, const int* __restrict__ ltype_g,
    const float* __restrict__ pemb, const float* __restrict__ lemb,
    const float* __restrict__ W1, const float* __restrict__ b1,
    const float* __restrict__ W2, const float* __restrict__ W3,
    uint2* __restrict__ rec, unsigned* __restrict__ cnt,
    _Float16* __restrict__ wt1e, _Float16* __restrict__ wt2t,
    _Float16* __restrict__ wt3t, float* __restrict__ acc)
{
  int blk = blockIdx.x, tid = threadIdx.x;

  if (blk < 8) {
    // ---- compaction: thread t owns protein atoms 2t, 2t+1 ----------------
    int b = blk;
    int w = tid >> 6, lane = tid & 63;
    __shared__ float slig[NL * 3];
    __shared__ int slt[NL];
    __shared__ unsigned wtot[4];

    if (tid < NL * 3) slig[tid] = lpos[b * NL * 3 + tid];
    if (tid < NL) slt[tid] = ltype_g[b * NL + tid];
    __syncthreads();

    const float* pp = ppos + (size_t)(b * NP + 2 * tid) * 3;
    float p0x = pp[0], p0y = pp[1], p0z = pp[2];
    float p1x = pp[3], p1y = pp[4], p1z = pp[5];
    unsigned pt0 = (unsigned)ptype_g[b * NP + 2 * tid];
    unsigned pt1 = (unsigned)ptype_g[b * NP + 2 * tid + 1];

    unsigned long long m0 = 0ull, m1 = 0ull;
    for (int l = 0; l < NL; ++l) {
      float qx = slig[3 * l + 0], qy = slig[3 * l + 1], qz = slig[3 * l + 2];
      float dx0 = p0x - qx, dy0 = p0y - qy, dz0 = p0z - qz;
      float dx1 = p1x - qx, dy1 = p1y - qy, dz1 = p1z - qz;
      bool v0 = sqrtf(dx0 * dx0 + dy0 * dy0 + dz0 * dz0) < 8.0f;
      bool v1 = sqrtf(dx1 * dx1 + dy1 * dy1 + dz1 * dz1) < 8.0f;
      m0 |= ((unsigned long long)v0) << l;
      m1 |= ((unsigned long long)v1) << l;
    }
    unsigned count = (unsigned)(__popcll(m0) + __popcll(m1));

    unsigned inc = count;
    #pragma unroll
    for (int d = 1; d < 64; d <<= 1) {
      unsigned v = __shfl_up(inc, d);
      if (lane >= d) inc += v;
    }
    if (lane == 63) wtot[w] = inc;
    __syncthreads();
    unsigned wbase = 0;
    for (int i = 0; i < w; ++i) wbase += wtot[i];
    unsigned base = wbase + inc - count;          // exclusive prefix
    if (tid == 255) cnt[b] = wbase + inc;

    uint2* dst = rec + (size_t)b * PAIRS_CAP;
    unsigned long long mm = m0;
    while (mm) {
      int l = __builtin_ctzll(mm); mm &= mm - 1ull;
      float dx = p0x - slig[3 * l], dy = p0y - slig[3 * l + 1], dz = p0z - slig[3 * l + 2];
      float d = sqrtf(dx * dx + dy * dy + dz * dz);
      dst[base++] = (uint2){__float_as_uint(d), (pt0 << 16) | (unsigned)slt[l]};
    }
    mm = m1;
    while (mm) {
      int l = __builtin_ctzll(mm); mm &= mm - 1ull;
      float dx = p1x - slig[3 * l], dy = p1y - slig[3 * l + 1], dz = p1z - slig[3 * l + 2];
      float d = sqrtf(dx * dx + dy * dy + dz * dz);
      dst[base++] = (uint2){__float_as_uint(d), (pt1 << 16) | (unsigned)slt[l]};
    }
    return;
  }

  if (blk == 8) {
    for (int i = tid; i < NB * NH; i += 256) acc[i] = 0.0f;
    return;
  }

  if (blk < 105) {
    // ---- wt1e column k (only 128 threads active) -------------------------
    int k = blk - 9;
    if (tid >= NH) return;
    int c = tid;
    float v;
    if (k < 32) {
      v = W1[(2 * NH + k) * NH + c];
    } else if (k < 52) {
      int t = k - 32;
      float s = b1[c];
      for (int j = 0; j < NH; ++j)
        s = fmaf(pemb[t * NH + j], W1[j * NH + c], s);
      v = s;
    } else if (k < 68) {
      int t = k - 52;
      float s = 0.0f;
      for (int j = 0; j < NH; ++j)
        s = fmaf(lemb[t * NH + j], W1[(NH + j) * NH + c], s);
      v = s;
    } else {
      v = 0.0f;
    }
    wt1e[c * K1 + k] = (_Float16)v;
    return;
  }

  {
    // ---- wt2t/wt3t row k (transpose; only 128 threads active) ------------
    int k = blk - 105;
    if (tid >= NH) return;
    int c = tid;
    wt2t[c * NH + k] = (_Float16)W2[k * NH + c];
    wt3t[c * NH + k] = (_Float16)W3[k * NH + c];
    return;
  }
}

// ---------------------------------------------------------------------------
// Kernel B: MFMA pair MLP over packed pair records. One block per 64-pair
// chunk (grid 4096, ~57% exit immediately). 4 waves; wave cg owns cols
// [32cg,32cg+32). 16x16x32_f16 MFMA, fp32 acc. SINGLE 16KB LDS tile
// (read-all -> barrier -> write-in-place) -> 6 blocks/CU. XOR-swizzled
// (half_idx ^= (row&7)<<3) -> conflict-free ds_read_b128.
// C/D layout per m89: row = 16m + (lane>>4)*4 + reg, col = 16n + (lane&15).
// ---------------------------------------------------------------------------
__device__ __forceinline__ int swz(int row, int col) {
  return row * NH + (col ^ ((row & 7) << 3));   // half-index swizzle
}

__global__ __launch_bounds__(256, 6) void pair_mlp(
    const _Float16* __restrict__ wt1e, const _Float16* __restrict__ wt2t,
    const _Float16* __restrict__ wt3t,
    const float* __restrict__ b2, const float* __restrict__ b3,
    const uint2* __restrict__ rec, const unsigned* __restrict__ cnt,
    float* __restrict__ accum)
{
  __shared__ _Float16 sS[NL * NH];   // 16 KB single tile

  int tid = threadIdx.x;
  int cg = __builtin_amdgcn_readfirstlane(tid >> 6);
  int l  = tid & 63;
  int b     = blockIdx.x & 7;
  int chunk = blockIdx.x >> 3;

  unsigned total = cnt[b];
  if ((unsigned)(chunk * 64) >= total) return;

  int idx = chunk * 64 + l;
  int src = ((unsigned)idx < total) ? idx : 0;    // duplicate row 0 in tail
  uint2 rcd = rec[(size_t)b * PAIRS_CAP + src];   // ONE coalesced 8B load
  float dist = __uint_as_float(rcd.x);
  int pt = (int)(rcd.y >> 16), lt = (int)(rcd.y & 0xffffu);

  const float stepc = 8.0f / 31.0f;
  const float invw = 1.0f / (0.125f + 1e-8f);

  // --- build extended-A row l (0..31 rb | 32..51 pt-1hot | 52..67 lt-1hot
  // | 68..95 zero). Wave cg writes 16B chunks 3cg..3cg+2. -------------------
  for (int jj = 0; jj < 3; ++jj) {
    int ch = 3 * cg + jj;                         // wave-uniform
    h8 v;
    #pragma unroll
    for (int i = 0; i < 8; ++i) {
      int c = ch * 8 + i;
      float x;
      if (c < 32) { float t = (dist - stepc * (float)c) * invw; x = __expf(-0.5f * t * t); }
      else if (c < 52) x = (c - 32 == pt) ? 1.0f : 0.0f;
      else if (c < 68) x = (c - 52 == lt) ? 1.0f : 0.0f;
      else x = 0.0f;
      v[i] = (_Float16)x;
    }
    *(h8*)&sS[swz(l, ch * 8)] = v;
  }
  __syncthreads();

  int col0 = cg * 32 + (l & 15);                  // n=0 column for this lane
  int krow = 8 * (l >> 4);                        // k sub-row for A/B frags
  int g4 = (l >> 4) * 4;                          // C-frag row group

  // --- layer 1: K=96, reads sS (cols 0..95), writes h1 in place ------------
  {
    h8 B1[2][3];
    #pragma unroll
    for (int n = 0; n < 2; ++n)
      #pragma unroll
      for (int kk = 0; kk < 3; ++kk)
        B1[n][kk] = *(const h8*)&wt1e[(col0 + 16 * n) * K1 + 32 * kk + krow];

    f4 acc1[4][2];
    #pragma unroll
    for (int m = 0; m < 4; ++m)
      #pragma unroll
      for (int n = 0; n < 2; ++n)
        acc1[m][n] = (f4){0.0f, 0.0f, 0.0f, 0.0f};

    #pragma unroll
    for (int m = 0; m < 4; ++m) {
      int row = 16 * m + (l & 15);
      #pragma unroll
      for (int kk = 0; kk < 3; ++kk) {
        h8 a = *(const h8*)&sS[swz(row, 32 * kk + krow)];
        acc1[m][0] = __builtin_amdgcn_mfma_f32_16x16x32_f16(a, B1[0][kk], acc1[m][0], 0, 0, 0);
        acc1[m][1] = __builtin_amdgcn_mfma_f32_16x16x32_f16(a, B1[1][kk], acc1[m][1], 0, 0, 0);
      }
    }
    __syncthreads();                              // all reads of sS done
    #pragma unroll
    for (int m = 0; m < 4; ++m)
      #pragma unroll
      for (int n = 0; n < 2; ++n)
        #pragma unroll
        for (int r = 0; r < 4; ++r) {
          int row = 16 * m + g4 + r;
          sS[swz(row, cg * 32 + 16 * n + (l & 15))] =
              (_Float16)fmaxf(acc1[m][n][r], 0.0f);
        }
  }
  __syncthreads();

  // --- layer 2: K=128, reads sS, writes h2 in place ------------------------
  {
    h8 B2[2][4];
    #pragma unroll
    for (int n = 0; n < 2; ++n)
      #pragma unroll
      for (int kk = 0; kk < 4; ++kk)
        B2[n][kk] = *(const h8*)&wt2t[(col0 + 16 * n) * NH + 32 * kk + krow];

    float bias0 = b2[col0], bias1 = b2[col0 + 16];
    f4 acc2[4][2];
    #pragma unroll
    for (int m = 0; m < 4; ++m) {
      acc2[m][0] = (f4){bias0, bias0, bias0, bias0};
      acc2[m][1] = (f4){bias1, bias1, bias1, bias1};
    }
    #pragma unroll
    for (int m = 0; m < 4; ++m) {
      int row = 16 * m + (l & 15);
      #pragma unroll
      for (int kk = 0; kk < 4; ++kk) {
        h8 a = *(const h8*)&sS[swz(row, 32 * kk + krow)];
        acc2[m][0] = __builtin_amdgcn_mfma_f32_16x16x32_f16(a, B2[0][kk], acc2[m][0], 0, 0, 0);
        acc2[m][1] = __builtin_amdgcn_mfma_f32_16x16x32_f16(a, B2[1][kk], acc2[m][1], 0, 0, 0);
      }
    }
    __syncthreads();                              // all reads of sS done
    #pragma unroll
    for (int m = 0; m < 4; ++m)
      #pragma unroll
      for (int n = 0; n < 2; ++n)
        #pragma unroll
        for (int r = 0; r < 4; ++r) {
          int row = 16 * m + g4 + r;
          sS[swz(row, cg * 32 + 16 * n + (l & 15))] =
              (_Float16)fmaxf(acc2[m][n][r], 0.0f);
        }
  }
  __syncthreads();

  // --- layer 3: K=128, reads sS, masked column-sum -> atomics --------------
  {
    h8 B3[2][4];
    #pragma unroll
    for (int n = 0; n < 2; ++n)
      #pragma unroll
      for (int kk = 0; kk < 4; ++kk)
        B3[n][kk] = *(const h8*)&wt3t[(col0 + 16 * n) * NH + 32 * kk + krow];

    float bias0 = b3[col0], bias1 = b3[col0 + 16];
    f4 acc3[4][2];
    #pragma unroll
    for (int m = 0; m < 4; ++m) {
      acc3[m][0] = (f4){bias0, bias0, bias0, bias0};
      acc3[m][1] = (f4){bias1, bias1, bias1, bias1};
    }
    #pragma unroll
    for (int m = 0; m < 4; ++m) {
      int row = 16 * m + (l & 15);
      #pragma unroll
      for (int kk = 0; kk < 4; ++kk) {
        h8 a = *(const h8*)&sS[swz(row, 32 * kk + krow)];
        acc3[m][0] = __builtin_amdgcn_mfma_f32_16x16x32_f16(a, B3[0][kk], acc3[m][0], 0, 0, 0);
        acc3[m][1] = __builtin_amdgcn_mfma_f32_16x16x32_f16(a, B3[1][kk], acc3[m][1], 0, 0, 0);
      }
    }

    int rem = (int)total - chunk * 64;            // rows < rem are valid
    float cs0 = 0.0f, cs1 = 0.0f;
    #pragma unroll
    for (int m = 0; m < 4; ++m)
      #pragma unroll
      for (int r = 0; r < 4; ++r) {
        int row = 16 * m + g4 + r;
        bool ok = row < rem;
        cs0 += ok ? fmaxf(acc3[m][0][r], 0.0f) : 0.0f;
        cs1 += ok ? fmaxf(acc3[m][1][r], 0.0f) : 0.0f;
      }
    cs0 += __shfl_xor(cs0, 16); cs0 += __shfl_xor(cs0, 32);
    cs1 += __shfl_xor(cs1, 16); cs1 += __shfl_xor(cs1, 32);
    int g = l >> 4;
    if (g == 0)      atomicAdd(&accum[b * NH + cg * 32 + (l & 15)], cs0);
    else if (g == 1) atomicAdd(&accum[b * NH + cg * 32 + 16 + (l & 15)], cs1);
  }
}

// ---------------------------------------------------------------------------
// Kernel C: scoring head. One block per complex (grid=8), 128 threads.
// ---------------------------------------------------------------------------
__global__ __launch_bounds__(128) void score_head(
    const float* __restrict__ acc, const unsigned* __restrict__ cnt,
    const float* __restrict__ Wr1, const float* __restrict__ br1,
    const float* __restrict__ Wr2, const float* __restrict__ br2,
    float* __restrict__ out)
{
  int b = blockIdx.x;
  int tid = threadIdx.x;
  __shared__ float sr[NH];
  __shared__ float sv[NH];
  unsigned c = cnt[b];
  float denom = fmaxf((float)c, 1.0f);
  sr[tid] = acc[b * NH + tid] / denom;
  __syncthreads();
  float s = br1[tid];
  for (int k = 0; k < NH; ++k)
    s = fmaf(sr[k], Wr1[k * NH + tid], s);
  sv[tid] = fmaxf(s, 0.0f) * Wr2[tid];
  __syncthreads();
  if (tid == 0) {
    float sc = br2[0];
    for (int k = 0; k < NH; ++k) sc += sv[k];
    out[b] = (c > 0) ? sc : 0.0f;
  }
}

// ---------------------------------------------------------------------------
extern "C" void kernel_launch(void* const* d_in, const int* in_sizes, int n_in,
                              void* d_out, int out_size, void* d_ws, size_t ws_size,
                              hipStream_t stream)
{
  const float* ppos = (const float*)d_in[0];
  const float* lpos = (const float*)d_in[1];
  const float* pemb = (const float*)d_in[2];
  const float* lemb = (const float*)d_in[3];
  const float* W1   = (const float*)d_in[4];
  const float* b1   = (const float*)d_in[5];
  const float* W2   = (const float*)d_in[6];
  const float* b2   = (const float*)d_in[7];
  const float* W3   = (const float*)d_in[8];
  const float* b3   = (const float*)d_in[9];
  const float* Wr1  = (const float*)d_in[10];
  const float* br1  = (const float*)d_in[11];
  const float* Wr2  = (const float*)d_in[12];
  const float* br2  = (const float*)d_in[13];
  const int*   ptyp = (const int*)d_in[14];
  const int*   ltyp = (const int*)d_in[15];
  // d_in[16], d_in[17] (batch indices) unused: batches contiguous & uniform.

  float* ws  = (float*)d_ws;
  float* acc = ws;                          // 1024 f
  unsigned* cnt = (unsigned*)(ws + 1024);   // 8 u32 (pad to 1032)
  uint2* rec = (uint2*)(ws + 1032);         // 8*32768*8B = 2 MB (524288 f)
  _Float16* wt1e = (_Float16*)(ws + 1032 + 524288);                // 128*96 h
  _Float16* wt2t = (_Float16*)(ws + 1032 + 524288 + 6144);         // 128*128 h
  _Float16* wt3t = (_Float16*)(ws + 1032 + 524288 + 6144 + 8192);  // 128*128 h

  prep<<<233, 256, 0, stream>>>(ppos, lpos, ptyp, ltyp, pemb, lemb,
                                W1, b1, W2, W3,
                                rec, cnt, wt1e, wt2t, wt3t, acc);
  pair_mlp<<<NB * CHUNKS, 256, 0, stream>>>(wt1e, wt2t, wt3t, b2, b3,
                                            rec, cnt, acc);
  score_head<<<NB, 128, 0, stream>>>(acc, cnt, Wr1, br1, Wr2, br2, (float*)d_out);
}

// Round 8
// 62.121 us; speedup vs baseline: 1.3423x; 1.3423x over previous
//
#include <hip/hip_runtime.h>
#include <hip/hip_bf16.h>
#include <math.h>

// Problem constants (match reference)
#define NB 8
#define NP 512
#define NL 64
#define NH 128
#define NRB 32
#define NPT 20
#define NLT 16
#define PAIRS_CAP (NP * NL)      // 32768 pairs per complex max
#define CHUNKS 512               // PAIRS_CAP / 64
#define K1 96                    // extended layer-1 K: 32 rb + 20 pt + 16 lt + pad

typedef __attribute__((ext_vector_type(8))) _Float16 h8;
typedef __attribute__((ext_vector_type(4))) float f4;

// ---------------------------------------------------------------------------
// Kernel A: fused prep. Heterogeneous 233-block kernel, 256 threads each.
//  blk 0..7    : compaction -> packed pair records {dist, (pt<<16)|lt} (8B)
//  blk 8       : zero accumulators
//  blk 9..104  : pack wt1e column k (k<32: W1c^T copy; 32..51: TP row dot;
//                52..67: TL row dot; 68..95: zero)
//  blk 105..232: pack wt2t/wt3t row k (transpose of W2/W3)
// ---------------------------------------------------------------------------
__global__ __launch_bounds__(256) void prep(
    const float* __restrict__ ppos, const float* __restrict__ lpos,
    const int* __restrict__ ptype_g, const int* __restrict__ ltype_g,
    const float* __restrict__ pemb, const float* __restrict__ lemb,
    const float* __restrict__ W1, const float* __restrict__ b1,
    const float* __restrict__ W2, const float* __restrict__ W3,
    uint2* __restrict__ rec, unsigned* __restrict__ cnt,
    _Float16* __restrict__ wt1e, _Float16* __restrict__ wt2t,
    _Float16* __restrict__ wt3t, float* __restrict__ acc)
{
  int blk = blockIdx.x, tid = threadIdx.x;

  if (blk < 8) {
    // ---- compaction: thread t owns protein atoms 2t, 2t+1 ----------------
    int b = blk;
    int w = tid >> 6, lane = tid & 63;
    __shared__ float slig[NL * 3];
    __shared__ int slt[NL];
    __shared__ unsigned wtot[4];

    if (tid < NL * 3) slig[tid] = lpos[b * NL * 3 + tid];
    if (tid < NL) slt[tid] = ltype_g[b * NL + tid];
    __syncthreads();

    const float* pp = ppos + (size_t)(b * NP + 2 * tid) * 3;
    float p0x = pp[0], p0y = pp[1], p0z = pp[2];
    float p1x = pp[3], p1y = pp[4], p1z = pp[5];
    unsigned pt0 = (unsigned)ptype_g[b * NP + 2 * tid];
    unsigned pt1 = (unsigned)ptype_g[b * NP + 2 * tid + 1];

    unsigned long long m0 = 0ull, m1 = 0ull;
    for (int l = 0; l < NL; ++l) {
      float qx = slig[3 * l + 0], qy = slig[3 * l + 1], qz = slig[3 * l + 2];
      float dx0 = p0x - qx, dy0 = p0y - qy, dz0 = p0z - qz;
      float dx1 = p1x - qx, dy1 = p1y - qy, dz1 = p1z - qz;
      bool v0 = sqrtf(dx0 * dx0 + dy0 * dy0 + dz0 * dz0) < 8.0f;
      bool v1 = sqrtf(dx1 * dx1 + dy1 * dy1 + dz1 * dz1) < 8.0f;
      m0 |= ((unsigned long long)v0) << l;
      m1 |= ((unsigned long long)v1) << l;
    }
    unsigned count = (unsigned)(__popcll(m0) + __popcll(m1));

    unsigned inc = count;
    #pragma unroll
    for (int d = 1; d < 64; d <<= 1) {
      unsigned v = __shfl_up(inc, d);
      if (lane >= d) inc += v;
    }
    if (lane == 63) wtot[w] = inc;
    __syncthreads();
    unsigned wbase = 0;
    for (int i = 0; i < w; ++i) wbase += wtot[i];
    unsigned base = wbase + inc - count;          // exclusive prefix
    if (tid == 255) cnt[b] = wbase + inc;

    uint2* dst = rec + (size_t)b * PAIRS_CAP;
    unsigned long long mm = m0;
    while (mm) {
      int l = __builtin_ctzll(mm); mm &= mm - 1ull;
      float dx = p0x - slig[3 * l], dy = p0y - slig[3 * l + 1], dz = p0z - slig[3 * l + 2];
      float d = sqrtf(dx * dx + dy * dy + dz * dz);
      dst[base++] = (uint2){__float_as_uint(d), (pt0 << 16) | (unsigned)slt[l]};
    }
    mm = m1;
    while (mm) {
      int l = __builtin_ctzll(mm); mm &= mm - 1ull;
      float dx = p1x - slig[3 * l], dy = p1y - slig[3 * l + 1], dz = p1z - slig[3 * l + 2];
      float d = sqrtf(dx * dx + dy * dy + dz * dz);
      dst[base++] = (uint2){__float_as_uint(d), (pt1 << 16) | (unsigned)slt[l]};
    }
    return;
  }

  if (blk == 8) {
    for (int i = tid; i < NB * NH; i += 256) acc[i] = 0.0f;
    return;
  }

  if (blk < 105) {
    // ---- wt1e column k (only 128 threads active) -------------------------
    int k = blk - 9;
    if (tid >= NH) return;
    int c = tid;
    float v;
    if (k < 32) {
      v = W1[(2 * NH + k) * NH + c];
    } else if (k < 52) {
      int t = k - 32;
      float s = b1[c];
      for (int j = 0; j < NH; ++j)
        s = fmaf(pemb[t * NH + j], W1[j * NH + c], s);
      v = s;
    } else if (k < 68) {
      int t = k - 52;
      float s = 0.0f;
      for (int j = 0; j < NH; ++j)
        s = fmaf(lemb[t * NH + j], W1[(NH + j) * NH + c], s);
      v = s;
    } else {
      v = 0.0f;
    }
    wt1e[c * K1 + k] = (_Float16)v;
    return;
  }

  {
    // ---- wt2t/wt3t row k (transpose; only 128 threads active) ------------
    int k = blk - 105;
    if (tid >= NH) return;
    int c = tid;
    wt2t[c * NH + k] = (_Float16)W2[k * NH + c];
    wt3t[c * NH + k] = (_Float16)W3[k * NH + c];
    return;
  }
}

// ---------------------------------------------------------------------------
// Kernel B: MFMA pair MLP over packed pair records. One block per 64-pair
// chunk (grid 4096, ~57% exit at the cnt check). 4 waves; wave cg owns cols
// [32cg,32cg+32). 16x16x32_f16 MFMA, fp32 acc. PING-PONG 2x16KB LDS tiles
// -> exactly one barrier per phase (build|L1|L2), 3 total. B-frag weight
// loads hoisted into the PREVIOUS phase so global latency hides under the
// epilogue writes + barrier. launch_bounds(256,4): VGPR cap 128 (R7's cap
// of 6 blocks/CU squeezed VGPRs to 40 and serialized everything).
// XOR swizzle (half_idx ^= (row&7)<<3) -> conflict-free ds_read_b128.
// C/D layout per m89: row = 16m + (lane>>4)*4 + reg, col = 16n + (lane&15).
// ---------------------------------------------------------------------------
__device__ __forceinline__ int swz(int row, int col) {
  return row * NH + (col ^ ((row & 7) << 3));   // half-index swizzle
}

__global__ __launch_bounds__(256, 4) void pair_mlp(
    const _Float16* __restrict__ wt1e, const _Float16* __restrict__ wt2t,
    const _Float16* __restrict__ wt3t,
    const float* __restrict__ b2, const float* __restrict__ b3,
    const uint2* __restrict__ rec, const unsigned* __restrict__ cnt,
    float* __restrict__ accum)
{
  __shared__ _Float16 sX[NL * NH];   // 16 KB: ext-A tile, then h2
  __shared__ _Float16 sY[NL * NH];   // 16 KB: h1 tile

  int tid = threadIdx.x;
  int cg = __builtin_amdgcn_readfirstlane(tid >> 6);
  int l  = tid & 63;
  int b     = blockIdx.x & 7;
  int chunk = blockIdx.x >> 3;

  unsigned total = cnt[b];
  if ((unsigned)(chunk * 64) >= total) return;

  int col0 = cg * 32 + (l & 15);                  // n=0 column for this lane
  int krow = 8 * (l >> 4);                        // k sub-row for A/B frags
  int g4 = (l >> 4) * 4;                          // C-frag row group

  // --- hoist layer-1 B-frags (latency hidden under build + barrier) --------
  h8 B1[2][3];
  #pragma unroll
  for (int n = 0; n < 2; ++n)
    #pragma unroll
    for (int kk = 0; kk < 3; ++kk)
      B1[n][kk] = *(const h8*)&wt1e[(col0 + 16 * n) * K1 + 32 * kk + krow];

  int idx = chunk * 64 + l;
  int src = ((unsigned)idx < total) ? idx : 0;    // duplicate row 0 in tail
  uint2 rcd = rec[(size_t)b * PAIRS_CAP + src];   // ONE coalesced 8B load
  float dist = __uint_as_float(rcd.x);
  int pt = (int)(rcd.y >> 16), lt = (int)(rcd.y & 0xffffu);

  const float stepc = 8.0f / 31.0f;
  const float invw = 1.0f / (0.125f + 1e-8f);

  // --- build extended-A row l (0..31 rb | 32..51 pt-1hot | 52..67 lt-1hot
  // | 68..95 zero) into sX. Wave cg writes 16B chunks 3cg..3cg+2. -----------
  for (int jj = 0; jj < 3; ++jj) {
    int ch = 3 * cg + jj;                         // wave-uniform
    h8 v;
    #pragma unroll
    for (int i = 0; i < 8; ++i) {
      int c = ch * 8 + i;
      float x;
      if (c < 32) { float t = (dist - stepc * (float)c) * invw; x = __expf(-0.5f * t * t); }
      else if (c < 52) x = (c - 32 == pt) ? 1.0f : 0.0f;
      else if (c < 68) x = (c - 52 == lt) ? 1.0f : 0.0f;
      else x = 0.0f;
      v[i] = (_Float16)x;
    }
    *(h8*)&sX[swz(l, ch * 8)] = v;
  }
  __syncthreads();                                // barrier 1: ext-A ready

  // --- layer 1: K=96, reads sX, writes h1 -> sY ----------------------------
  {
    f4 acc1[4][2];
    #pragma unroll
    for (int m = 0; m < 4; ++m)
      #pragma unroll
      for (int n = 0; n < 2; ++n)
        acc1[m][n] = (f4){0.0f, 0.0f, 0.0f, 0.0f};

    #pragma unroll
    for (int m = 0; m < 4; ++m) {
      int row = 16 * m + (l & 15);
      #pragma unroll
      for (int kk = 0; kk < 3; ++kk) {
        h8 a = *(const h8*)&sX[swz(row, 32 * kk + krow)];
        acc1[m][0] = __builtin_amdgcn_mfma_f32_16x16x32_f16(a, B1[0][kk], acc1[m][0], 0, 0, 0);
        acc1[m][1] = __builtin_amdgcn_mfma_f32_16x16x32_f16(a, B1[1][kk], acc1[m][1], 0, 0, 0);
      }
    }

    // prefetch layer-2 B-frags while L1 epilogue + barrier drain
    h8 B2[2][4];
    #pragma unroll
    for (int n = 0; n < 2; ++n)
      #pragma unroll
      for (int kk = 0; kk < 4; ++kk)
        B2[n][kk] = *(const h8*)&wt2t[(col0 + 16 * n) * NH + 32 * kk + krow];
    float bias20 = b2[col0], bias21 = b2[col0 + 16];

    #pragma unroll
    for (int m = 0; m < 4; ++m)
      #pragma unroll
      for (int n = 0; n < 2; ++n)
        #pragma unroll
        for (int r = 0; r < 4; ++r) {
          int row = 16 * m + g4 + r;
          sY[swz(row, cg * 32 + 16 * n + (l & 15))] =
              (_Float16)fmaxf(acc1[m][n][r], 0.0f);
        }
    __syncthreads();                              // barrier 2: h1 ready

    // --- layer 2: K=128, reads sY, writes h2 -> sX (all sX reads done) -----
    f4 acc2[4][2];
    #pragma unroll
    for (int m = 0; m < 4; ++m) {
      acc2[m][0] = (f4){bias20, bias20, bias20, bias20};
      acc2[m][1] = (f4){bias21, bias21, bias21, bias21};
    }
    #pragma unroll
    for (int m = 0; m < 4; ++m) {
      int row = 16 * m + (l & 15);
      #pragma unroll
      for (int kk = 0; kk < 4; ++kk) {
        h8 a = *(const h8*)&sY[swz(row, 32 * kk + krow)];
        acc2[m][0] = __builtin_amdgcn_mfma_f32_16x16x32_f16(a, B2[0][kk], acc2[m][0], 0, 0, 0);
        acc2[m][1] = __builtin_amdgcn_mfma_f32_16x16x32_f16(a, B2[1][kk], acc2[m][1], 0, 0, 0);
      }
    }

    // prefetch layer-3 B-frags while L2 epilogue + barrier drain
    h8 B3[2][4];
    #pragma unroll
    for (int n = 0; n < 2; ++n)
      #pragma unroll
      for (int kk = 0; kk < 4; ++kk)
        B3[n][kk] = *(const h8*)&wt3t[(col0 + 16 * n) * NH + 32 * kk + krow];
    float bias30 = b3[col0], bias31 = b3[col0 + 16];

    #pragma unroll
    for (int m = 0; m < 4; ++m)
      #pragma unroll
      for (int n = 0; n < 2; ++n)
        #pragma unroll
        for (int r = 0; r < 4; ++r) {
          int row = 16 * m + g4 + r;
          sX[swz(row, cg * 32 + 16 * n + (l & 15))] =
              (_Float16)fmaxf(acc2[m][n][r], 0.0f);
        }
    __syncthreads();                              // barrier 3: h2 ready

    // --- layer 3: K=128, reads sX, masked column-sum -> atomics ------------
    f4 acc3[4][2];
    #pragma unroll
    for (int m = 0; m < 4; ++m) {
      acc3[m][0] = (f4){bias30, bias30, bias30, bias30};
      acc3[m][1] = (f4){bias31, bias31, bias31, bias31};
    }
    #pragma unroll
    for (int m = 0; m < 4; ++m) {
      int row = 16 * m + (l & 15);
      #pragma unroll
      for (int kk = 0; kk < 4; ++kk) {
        h8 a = *(const h8*)&sX[swz(row, 32 * kk + krow)];
        acc3[m][0] = __builtin_amdgcn_mfma_f32_16x16x32_f16(a, B3[0][kk], acc3[m][0], 0, 0, 0);
        acc3[m][1] = __builtin_amdgcn_mfma_f32_16x16x32_f16(a, B3[1][kk], acc3[m][1], 0, 0, 0);
      }
    }

    int rem = (int)total - chunk * 64;            // rows < rem are valid
    float cs0 = 0.0f, cs1 = 0.0f;
    #pragma unroll
    for (int m = 0; m < 4; ++m)
      #pragma unroll
      for (int r = 0; r < 4; ++r) {
        int row = 16 * m + g4 + r;
        bool ok = row < rem;
        cs0 += ok ? fmaxf(acc3[m][0][r], 0.0f) : 0.0f;
        cs1 += ok ? fmaxf(acc3[m][1][r], 0.0f) : 0.0f;
      }
    cs0 += __shfl_xor(cs0, 16); cs0 += __shfl_xor(cs0, 32);
    cs1 += __shfl_xor(cs1, 16); cs1 += __shfl_xor(cs1, 32);
    int g = l >> 4;
    if (g == 0)      atomicAdd(&accum[b * NH + cg * 32 + (l & 15)], cs0);
    else if (g == 1) atomicAdd(&accum[b * NH + cg * 32 + 16 + (l & 15)], cs1);
  }
}

// ---------------------------------------------------------------------------
// Kernel C: scoring head. One block per complex (grid=8), 128 threads.
// ---------------------------------------------------------------------------
__global__ __launch_bounds__(128) void score_head(
    const float* __restrict__ acc, const unsigned* __restrict__ cnt,
    const float* __restrict__ Wr1, const float* __restrict__ br1,
    const float* __restrict__ Wr2, const float* __restrict__ br2,
    float* __restrict__ out)
{
  int b = blockIdx.x;
  int tid = threadIdx.x;
  __shared__ float sr[NH];
  __shared__ float sv[NH];
  unsigned c = cnt[b];
  float denom = fmaxf((float)c, 1.0f);
  sr[tid] = acc[b * NH + tid] / denom;
  __syncthreads();
  float s = br1[tid];
  for (int k = 0; k < NH; ++k)
    s = fmaf(sr[k], Wr1[k * NH + tid], s);
  sv[tid] = fmaxf(s, 0.0f) * Wr2[tid];
  __syncthreads();
  if (tid == 0) {
    float sc = br2[0];
    for (int k = 0; k < NH; ++k) sc += sv[k];
    out[b] = (c > 0) ? sc : 0.0f;
  }
}

// ---------------------------------------------------------------------------
extern "C" void kernel_launch(void* const* d_in, const int* in_sizes, int n_in,
                              void* d_out, int out_size, void* d_ws, size_t ws_size,
                              hipStream_t stream)
{
  const float* ppos = (const float*)d_in[0];
  const float* lpos = (const float*)d_in[1];
  const float* pemb = (const float*)d_in[2];
  const float* lemb = (const float*)d_in[3];
  const float* W1   = (const float*)d_in[4];
  const float* b1   = (const float*)d_in[5];
  const float* W2   = (const float*)d_in[6];
  const float* b2   = (const float*)d_in[7];
  const float* W3   = (const float*)d_in[8];
  const float* b3   = (const float*)d_in[9];
  const float* Wr1  = (const float*)d_in[10];
  const float* br1  = (const float*)d_in[11];
  const float* Wr2  = (const float*)d_in[12];
  const float* br2  = (const float*)d_in[13];
  const int*   ptyp = (const int*)d_in[14];
  const int*   ltyp = (const int*)d_in[15];
  // d_in[16], d_in[17] (batch indices) unused: batches contiguous & uniform.

  float* ws  = (float*)d_ws;
  float* acc = ws;                          // 1024 f
  unsigned* cnt = (unsigned*)(ws + 1024);   // 8 u32 (pad to 1032)
  uint2* rec = (uint2*)(ws + 1032);         // 8*32768*8B = 2 MB (524288 f)
  _Float16* wt1e = (_Float16*)(ws + 1032 + 524288);                // 128*96 h
  _Float16* wt2t = (_Float16*)(ws + 1032 + 524288 + 6144);         // 128*128 h
  _Float16* wt3t = (_Float16*)(ws + 1032 + 524288 + 6144 + 8192);  // 128*128 h

  prep<<<233, 256, 0, stream>>>(ppos, lpos, ptyp, ltyp, pemb, lemb,
                                W1, b1, W2, W3,
                                rec, cnt, wt1e, wt2t, wt3t, acc);
  pair_mlp<<<NB * CHUNKS, 256, 0, stream>>>(wt1e, wt2t, wt3t, b2, b3,
                                            rec, cnt, acc);
  score_head<<<NB, 128, 0, stream>>>(acc, cnt, Wr1, br1, Wr2, br2, (float*)d_out);
}

// Round 9
// 57.722 us; speedup vs baseline: 1.4446x; 1.0762x over previous
//
#include <hip/hip_runtime.h>
#include <hip/hip_bf16.h>
#include <math.h>

// Problem constants (match reference)
#define NB 8
#define NP 512
#define NL 64
#define NH 128
#define NRB 32
#define NPT 20
#define NLT 16
#define PAIRS_CAP (NP * NL)      // 32768 pairs per complex max
#define CHUNKS 512               // PAIRS_CAP / 64
#define K1 96                    // extended layer-1 K: 32 rb + 20 pt + 16 lt + pad

typedef __attribute__((ext_vector_type(8))) _Float16 h8;
typedef __attribute__((ext_vector_type(4))) float f4;

// ---------------------------------------------------------------------------
// Kernel A: fused prep. Heterogeneous 233-block kernel, 256 threads each.
//  blk 0..7    : compaction -> packed pair records {dist, (pt<<16)|lt} (8B)
//  blk 8       : zero accumulators
//  blk 9..104  : pack wt1e column k (k<32: W1c^T copy; 32..51: TP row dot;
//                52..67: TL row dot; 68..95: zero)
//  blk 105..232: pack wt2t/wt3t row k (transpose of W2/W3)
// ---------------------------------------------------------------------------
__global__ __launch_bounds__(256) void prep(
    const float* __restrict__ ppos, const float* __restrict__ lpos,
    const int* __restrict__ ptype_g, const int* __restrict__ ltype_g,
    const float* __restrict__ pemb, const float* __restrict__ lemb,
    const float* __restrict__ W1, const float* __restrict__ b1,
    const float* __restrict__ W2, const float* __restrict__ W3,
    uint2* __restrict__ rec, unsigned* __restrict__ cnt,
    _Float16* __restrict__ wt1e, _Float16* __restrict__ wt2t,
    _Float16* __restrict__ wt3t, float* __restrict__ acc)
{
  int blk = blockIdx.x, tid = threadIdx.x;

  if (blk < 8) {
    // ---- compaction: thread t owns protein atoms 2t, 2t+1 ----------------
    int b = blk;
    int w = tid >> 6, lane = tid & 63;
    __shared__ float slig[NL * 3];
    __shared__ int slt[NL];
    __shared__ unsigned wtot[4];

    if (tid < NL * 3) slig[tid] = lpos[b * NL * 3 + tid];
    if (tid < NL) slt[tid] = ltype_g[b * NL + tid];
    __syncthreads();

    const float* pp = ppos + (size_t)(b * NP + 2 * tid) * 3;
    float p0x = pp[0], p0y = pp[1], p0z = pp[2];
    float p1x = pp[3], p1y = pp[4], p1z = pp[5];
    unsigned pt0 = (unsigned)ptype_g[b * NP + 2 * tid];
    unsigned pt1 = (unsigned)ptype_g[b * NP + 2 * tid + 1];

    unsigned long long m0 = 0ull, m1 = 0ull;
    for (int l = 0; l < NL; ++l) {
      float qx = slig[3 * l + 0], qy = slig[3 * l + 1], qz = slig[3 * l + 2];
      float dx0 = p0x - qx, dy0 = p0y - qy, dz0 = p0z - qz;
      float dx1 = p1x - qx, dy1 = p1y - qy, dz1 = p1z - qz;
      bool v0 = sqrtf(dx0 * dx0 + dy0 * dy0 + dz0 * dz0) < 8.0f;
      bool v1 = sqrtf(dx1 * dx1 + dy1 * dy1 + dz1 * dz1) < 8.0f;
      m0 |= ((unsigned long long)v0) << l;
      m1 |= ((unsigned long long)v1) << l;
    }
    unsigned count = (unsigned)(__popcll(m0) + __popcll(m1));

    unsigned inc = count;
    #pragma unroll
    for (int d = 1; d < 64; d <<= 1) {
      unsigned v = __shfl_up(inc, d);
      if (lane >= d) inc += v;
    }
    if (lane == 63) wtot[w] = inc;
    __syncthreads();
    unsigned wbase = 0;
    for (int i = 0; i < w; ++i) wbase += wtot[i];
    unsigned base = wbase + inc - count;          // exclusive prefix
    if (tid == 255) cnt[b] = wbase + inc;

    uint2* dst = rec + (size_t)b * PAIRS_CAP;
    unsigned long long mm = m0;
    while (mm) {
      int l = __builtin_ctzll(mm); mm &= mm - 1ull;
      float dx = p0x - slig[3 * l], dy = p0y - slig[3 * l + 1], dz = p0z - slig[3 * l + 2];
      float d = sqrtf(dx * dx + dy * dy + dz * dz);
      dst[base++] = (uint2){__float_as_uint(d), (pt0 << 16) | (unsigned)slt[l]};
    }
    mm = m1;
    while (mm) {
      int l = __builtin_ctzll(mm); mm &= mm - 1ull;
      float dx = p1x - slig[3 * l], dy = p1y - slig[3 * l + 1], dz = p1z - slig[3 * l + 2];
      float d = sqrtf(dx * dx + dy * dy + dz * dz);
      dst[base++] = (uint2){__float_as_uint(d), (pt1 << 16) | (unsigned)slt[l]};
    }
    return;
  }

  if (blk == 8) {
    for (int i = tid; i < NB * NH; i += 256) acc[i] = 0.0f;
    return;
  }

  if (blk < 105) {
    // ---- wt1e column k (only 128 threads active) -------------------------
    int k = blk - 9;
    if (tid >= NH) return;
    int c = tid;
    float v;
    if (k < 32) {
      v = W1[(2 * NH + k) * NH + c];
    } else if (k < 52) {
      int t = k - 32;
      float s = b1[c];
      for (int j = 0; j < NH; ++j)
        s = fmaf(pemb[t * NH + j], W1[j * NH + c], s);
      v = s;
    } else if (k < 68) {
      int t = k - 52;
      float s = 0.0f;
      for (int j = 0; j < NH; ++j)
        s = fmaf(lemb[t * NH + j], W1[(NH + j) * NH + c], s);
      v = s;
    } else {
      v = 0.0f;
    }
    wt1e[c * K1 + k] = (_Float16)v;
    return;
  }

  {
    // ---- wt2t/wt3t row k (transpose; only 128 threads active) ------------
    int k = blk - 105;
    if (tid >= NH) return;
    int c = tid;
    wt2t[c * NH + k] = (_Float16)W2[k * NH + c];
    wt3t[c * NH + k] = (_Float16)W3[k * NH + c];
    return;
  }
}

// ---------------------------------------------------------------------------
// Kernel B: MFMA pair MLP — R5-exact structure (the best measured config:
// 2 static LDS tiles, B-frags loaded at layer start, R5 barrier placement,
// VGPR ~64, 4 blocks/CU) with ONE delta: rec-record prologue (1 coalesced
// 8B load replaces 9 scattered gathers; dist bitwise-identical).
// Wave cg owns cols [32cg,32cg+32); 16x16x32_f16 MFMA, fp32 acc; XOR
// swizzle (half_idx ^= (row&7)<<3) -> conflict-free ds_read_b128.
// C/D layout per m89: row = 16m + (lane>>4)*4 + reg, col = 16n + (lane&15).
// ---------------------------------------------------------------------------
__device__ __forceinline__ int swz(int row, int col) {
  return row * NH + (col ^ ((row & 7) << 3));   // half-index swizzle
}

__global__ __launch_bounds__(256, 4) void pair_mlp(
    const _Float16* __restrict__ wt1e, const _Float16* __restrict__ wt2t,
    const _Float16* __restrict__ wt3t,
    const float* __restrict__ b2, const float* __restrict__ b3,
    const uint2* __restrict__ rec, const unsigned* __restrict__ cnt,
    float* __restrict__ accum)
{
  __shared__ _Float16 sA[NL * NH];   // 16 KB: h1 tile
  __shared__ _Float16 sB[NL * NH];   // 16 KB: ext-A tile, then h2 tile

  int tid = threadIdx.x;
  int cg = __builtin_amdgcn_readfirstlane(tid >> 6);
  int l  = tid & 63;
  int b     = blockIdx.x & 7;
  int chunk = blockIdx.x >> 3;

  unsigned total = cnt[b];
  if ((unsigned)(chunk * 64) >= total) return;

  int idx = chunk * 64 + l;
  int src = ((unsigned)idx < total) ? idx : 0;    // duplicate row 0 in tail
  uint2 rcd = rec[(size_t)b * PAIRS_CAP + src];   // ONE coalesced 8B load
  float dist = __uint_as_float(rcd.x);
  int pt = (int)(rcd.y >> 16), lt = (int)(rcd.y & 0xffffu);

  const float stepc = 8.0f / 31.0f;
  const float invw = 1.0f / (0.125f + 1e-8f);

  // --- build extended-A row l (0..31 rb | 32..51 pt-1hot | 52..67 lt-1hot
  // | 68..95 zero) into sB. Wave cg writes 16B chunks 3cg..3cg+2. -----------
  for (int jj = 0; jj < 3; ++jj) {
    int ch = 3 * cg + jj;                         // wave-uniform
    h8 v;
    #pragma unroll
    for (int i = 0; i < 8; ++i) {
      int c = ch * 8 + i;
      float x;
      if (c < 32) { float t = (dist - stepc * (float)c) * invw; x = __expf(-0.5f * t * t); }
      else if (c < 52) x = (c - 32 == pt) ? 1.0f : 0.0f;
      else if (c < 68) x = (c - 52 == lt) ? 1.0f : 0.0f;
      else x = 0.0f;
      v[i] = (_Float16)x;
    }
    *(h8*)&sB[swz(l, ch * 8)] = v;
  }
  __syncthreads();

  int col0 = cg * 32 + (l & 15);                  // n=0 column for this lane
  int krow = 8 * (l >> 4);                        // k sub-row for A/B frags
  int g4 = (l >> 4) * 4;                          // C-frag row group

  // --- layer 1: K=96, reads sB(ext-A tile), writes sA ----------------------
  {
    h8 B1[2][3];
    #pragma unroll
    for (int n = 0; n < 2; ++n)
      #pragma unroll
      for (int kk = 0; kk < 3; ++kk)
        B1[n][kk] = *(const h8*)&wt1e[(col0 + 16 * n) * K1 + 32 * kk + krow];

    f4 acc1[4][2];
    #pragma unroll
    for (int m = 0; m < 4; ++m)
      #pragma unroll
      for (int n = 0; n < 2; ++n)
        acc1[m][n] = (f4){0.0f, 0.0f, 0.0f, 0.0f};

    #pragma unroll
    for (int m = 0; m < 4; ++m) {
      int row = 16 * m + (l & 15);
      #pragma unroll
      for (int kk = 0; kk < 3; ++kk) {
        h8 a = *(const h8*)&sB[swz(row, 32 * kk + krow)];
        acc1[m][0] = __builtin_amdgcn_mfma_f32_16x16x32_f16(a, B1[0][kk], acc1[m][0], 0, 0, 0);
        acc1[m][1] = __builtin_amdgcn_mfma_f32_16x16x32_f16(a, B1[1][kk], acc1[m][1], 0, 0, 0);
      }
    }
    #pragma unroll
    for (int m = 0; m < 4; ++m)
      #pragma unroll
      for (int n = 0; n < 2; ++n)
        #pragma unroll
        for (int r = 0; r < 4; ++r) {
          int row = 16 * m + g4 + r;
          sA[swz(row, cg * 32 + 16 * n + (l & 15))] =
              (_Float16)fmaxf(acc1[m][n][r], 0.0f);
        }
  }
  __syncthreads();

  // --- layer 2: K=128, reads sA, writes sB ---------------------------------
  {
    h8 B2[2][4];
    #pragma unroll
    for (int n = 0; n < 2; ++n)
      #pragma unroll
      for (int kk = 0; kk < 4; ++kk)
        B2[n][kk] = *(const h8*)&wt2t[(col0 + 16 * n) * NH + 32 * kk + krow];

    float bias0 = b2[col0], bias1 = b2[col0 + 16];
    f4 acc2[4][2];
    #pragma unroll
    for (int m = 0; m < 4; ++m) {
      acc2[m][0] = (f4){bias0, bias0, bias0, bias0};
      acc2[m][1] = (f4){bias1, bias1, bias1, bias1};
    }
    #pragma unroll
    for (int m = 0; m < 4; ++m) {
      int row = 16 * m + (l & 15);
      #pragma unroll
      for (int kk = 0; kk < 4; ++kk) {
        h8 a = *(const h8*)&sA[swz(row, 32 * kk + krow)];
        acc2[m][0] = __builtin_amdgcn_mfma_f32_16x16x32_f16(a, B2[0][kk], acc2[m][0], 0, 0, 0);
        acc2[m][1] = __builtin_amdgcn_mfma_f32_16x16x32_f16(a, B2[1][kk], acc2[m][1], 0, 0, 0);
      }
    }
    __syncthreads();                              // all reads of sB done
    #pragma unroll
    for (int m = 0; m < 4; ++m)
      #pragma unroll
      for (int n = 0; n < 2; ++n)
        #pragma unroll
        for (int r = 0; r < 4; ++r) {
          int row = 16 * m + g4 + r;
          sB[swz(row, cg * 32 + 16 * n + (l & 15))] =
              (_Float16)fmaxf(acc2[m][n][r], 0.0f);
        }
  }
  __syncthreads();

  // --- layer 3: K=128, reads sB, masked column-sum -> atomics --------------
  {
    h8 B3[2][4];
    #pragma unroll
    for (int n = 0; n < 2; ++n)
      #pragma unroll
      for (int kk = 0; kk < 4; ++kk)
        B3[n][kk] = *(const h8*)&wt3t[(col0 + 16 * n) * NH + 32 * kk + krow];

    float bias0 = b3[col0], bias1 = b3[col0 + 16];
    f4 acc3[4][2];
    #pragma unroll
    for (int m = 0; m < 4; ++m) {
      acc3[m][0] = (f4){bias0, bias0, bias0, bias0};
      acc3[m][1] = (f4){bias1, bias1, bias1, bias1};
    }
    #pragma unroll
    for (int m = 0; m < 4; ++m) {
      int row = 16 * m + (l & 15);
      #pragma unroll
      for (int kk = 0; kk < 4; ++kk) {
        h8 a = *(const h8*)&sB[swz(row, 32 * kk + krow)];
        acc3[m][0] = __builtin_amdgcn_mfma_f32_16x16x32_f16(a, B3[0][kk], acc3[m][0], 0, 0, 0);
        acc3[m][1] = __builtin_amdgcn_mfma_f32_16x16x32_f16(a, B3[1][kk], acc3[m][1], 0, 0, 0);
      }
    }

    int rem = (int)total - chunk * 64;            // rows < rem are valid
    float cs0 = 0.0f, cs1 = 0.0f;
    #pragma unroll
    for (int m = 0; m < 4; ++m)
      #pragma unroll
      for (int r = 0; r < 4; ++r) {
        int row = 16 * m + g4 + r;
        bool ok = row < rem;
        cs0 += ok ? fmaxf(acc3[m][0][r], 0.0f) : 0.0f;
        cs1 += ok ? fmaxf(acc3[m][1][r], 0.0f) : 0.0f;
      }
    cs0 += __shfl_xor(cs0, 16); cs0 += __shfl_xor(cs0, 32);
    cs1 += __shfl_xor(cs1, 16); cs1 += __shfl_xor(cs1, 32);
    int g = l >> 4;
    if (g == 0)      atomicAdd(&accum[b * NH + cg * 32 + (l & 15)], cs0);
    else if (g == 1) atomicAdd(&accum[b * NH + cg * 32 + 16 + (l & 15)], cs1);
  }
}

// ---------------------------------------------------------------------------
// Kernel C: scoring head. One block per complex (grid=8), 128 threads.
// Final sum via shfl_xor butterfly (replaces tid0-serial 128-step LDS chain).
// ---------------------------------------------------------------------------
__global__ __launch_bounds__(128) void score_head(
    const float* __restrict__ acc, const unsigned* __restrict__ cnt,
    const float* __restrict__ Wr1, const float* __restrict__ br1,
    const float* __restrict__ Wr2, const float* __restrict__ br2,
    float* __restrict__ out)
{
  int b = blockIdx.x;
  int tid = threadIdx.x;
  __shared__ float sr[NH];
  __shared__ float wsum[2];
  unsigned c = cnt[b];
  float denom = fmaxf((float)c, 1.0f);
  sr[tid] = acc[b * NH + tid] / denom;
  __syncthreads();
  float s = br1[tid];
  for (int k = 0; k < NH; ++k)
    s = fmaf(sr[k], Wr1[k * NH + tid], s);
  float v = fmaxf(s, 0.0f) * Wr2[tid];
  // butterfly reduce across the 64-lane wave
  #pragma unroll
  for (int d = 1; d < 64; d <<= 1) v += __shfl_xor(v, d);
  if ((tid & 63) == 0) wsum[tid >> 6] = v;
  __syncthreads();
  if (tid == 0)
    out[b] = (c > 0) ? (wsum[0] + wsum[1] + br2[0]) : 0.0f;
}

// ---------------------------------------------------------------------------
extern "C" void kernel_launch(void* const* d_in, const int* in_sizes, int n_in,
                              void* d_out, int out_size, void* d_ws, size_t ws_size,
                              hipStream_t stream)
{
  const float* ppos = (const float*)d_in[0];
  const float* lpos = (const float*)d_in[1];
  const float* pemb = (const float*)d_in[2];
  const float* lemb = (const float*)d_in[3];
  const float* W1   = (const float*)d_in[4];
  const float* b1   = (const float*)d_in[5];
  const float* W2   = (const float*)d_in[6];
  const float* b2   = (const float*)d_in[7];
  const float* W3   = (const float*)d_in[8];
  const float* b3   = (const float*)d_in[9];
  const float* Wr1  = (const float*)d_in[10];
  const float* br1  = (const float*)d_in[11];
  const float* Wr2  = (const float*)d_in[12];
  const float* br2  = (const float*)d_in[13];
  const int*   ptyp = (const int*)d_in[14];
  const int*   ltyp = (const int*)d_in[15];
  // d_in[16], d_in[17] (batch indices) unused: batches contiguous & uniform.

  float* ws  = (float*)d_ws;
  float* acc = ws;                          // 1024 f
  unsigned* cnt = (unsigned*)(ws + 1024);   // 8 u32 (pad to 1032)
  uint2* rec = (uint2*)(ws + 1032);         // 8*32768*8B = 2 MB (524288 f)
  _Float16* wt1e = (_Float16*)(ws + 1032 + 524288);                // 128*96 h
  _Float16* wt2t = (_Float16*)(ws + 1032 + 524288 + 6144);         // 128*128 h
  _Float16* wt3t = (_Float16*)(ws + 1032 + 524288 + 6144 + 8192);  // 128*128 h

  prep<<<233, 256, 0, stream>>>(ppos, lpos, ptyp, ltyp, pemb, lemb,
                                W1, b1, W2, W3,
                                rec, cnt, wt1e, wt2t, wt3t, acc);
  pair_mlp<<<NB * CHUNKS, 256, 0, stream>>>(wt1e, wt2t, wt3t, b2, b3,
                                            rec, cnt, acc);
  score_head<<<NB, 128, 0, stream>>>(acc, cnt, Wr1, br1, Wr2, br2, (float*)d_out);
}